// Round 2
// baseline (1163.482 us; speedup 1.0000x reference)
//
#include <hip/hip_runtime.h>
#include <stdint.h>

#define G3          (1 << 24)                 // 16,777,216 cells per cascade
#define CASCADES    3
#define NUM_COORDS  (1 << 22)                 // 4,194,304
#define GRID_ELEMS  (CASCADES * G3)           // 50,331,648
#define BF_ELEMS    (GRID_ELEMS / 8)          // 6,291,456

// Bucketed scatter: bucket = 1024 cells (4 KB of grid region). Its 512-slot
// u64 entry array (4 KB) lives IN that exact region of d_out, so only the
// combine block that owns the bucket overwrites it later. Entry packing:
//   n(22 bits) << 42 | sigma_f32_bits(32) << 10 | cell_offset(10)
// n in the top bits => u64 atomic/LDS max == last-write-wins, sigma carried.
#define BUCKET_CELLS  1024
#define EPB           512                     // entry capacity = lambda+16sigma
#define NBUCKETS      (GRID_ELEMS / BUCKET_CELLS)   // 49,152
#define P2B           8                       // buckets per combine block
#define P2_CELLS      (P2B * BUCKET_CELLS)    // 8192 cells, 64 KB LDS

__device__ __forceinline__ uint32_t part1by2(uint32_t x) {
    x &= 0x3FFu;
    x = (x | (x << 16)) & 0x030000FFu;
    x = (x | (x << 8))  & 0x0300F00Fu;
    x = (x | (x << 4))  & 0x030C30C3u;
    x = (x | (x << 2))  & 0x09249249u;
    return x;
}

// ---------------- fast path ----------------

__global__ void zero_cnt(uint32_t* __restrict__ cnt) {
    int t = blockIdx.x * blockDim.x + threadIdx.x;   // [0, NBUCKETS/4)
    ((uint4*)cnt)[t] = make_uint4(0u, 0u, 0u, 0u);
}

__global__ void bucketize(const int* __restrict__ coords,
                          const float* __restrict__ sigmas,
                          uint32_t* __restrict__ cnt,
                          unsigned long long* __restrict__ entries) {
    int t = blockIdx.x * blockDim.x + threadIdx.x;   // [0, CASCADES*NUM_COORDS/4)
    const int4* c4 = (const int4*)coords;
    int4 a = c4[t * 3 + 0];   // x0 y0 z0 x1
    int4 b = c4[t * 3 + 1];   // y1 z1 x2 y2
    int4 c = c4[t * 3 + 2];   // z2 x3 y3 z3
    float4 s4 = ((const float4*)sigmas)[t];

    int g    = t * 4;
    int casc = g >> 22;                              // / NUM_COORDS
    uint32_t n0 = (uint32_t)(g & (NUM_COORDS - 1));
    uint32_t bucketBase = (uint32_t)casc * (G3 / BUCKET_CELLS);

    uint32_t code[4];
    code[0] = part1by2((uint32_t)a.x) | (part1by2((uint32_t)a.y) << 1) | (part1by2((uint32_t)a.z) << 2);
    code[1] = part1by2((uint32_t)a.w) | (part1by2((uint32_t)b.x) << 1) | (part1by2((uint32_t)b.y) << 2);
    code[2] = part1by2((uint32_t)b.z) | (part1by2((uint32_t)b.w) << 1) | (part1by2((uint32_t)c.x) << 2);
    code[3] = part1by2((uint32_t)c.y) | (part1by2((uint32_t)c.z) << 1) | (part1by2((uint32_t)c.w) << 2);
    float sg[4] = {s4.x, s4.y, s4.z, s4.w};

#pragma unroll
    for (int i = 0; i < 4; ++i) {
        uint32_t bkt = bucketBase + (code[i] >> 10);
        uint32_t off = code[i] & 1023u;
        uint32_t pos = atomicAdd(&cnt[bkt], 1u);
        if (pos < EPB) {
            unsigned long long e = ((unsigned long long)(n0 + (uint32_t)i) << 42)
                                 | ((unsigned long long)__float_as_uint(sg[i]) << 10)
                                 | (unsigned long long)off;
            entries[(size_t)bkt * EPB + pos] = e;
        }
    }
}

__global__ __launch_bounds__(256) void combine(float* __restrict__ out,
                                               const float* __restrict__ density,
                                               const uint32_t* __restrict__ cnt) {
    __shared__ unsigned long long lds[P2_CELLS];     // 64 KB
    int blk = blockIdx.x;                            // [0, NBUCKETS/P2B)
    size_t cellBase = (size_t)blk * P2_CELLS;

    for (int i = threadIdx.x; i < P2_CELLS; i += 256) lds[i] = 0ULL;
    __syncthreads();

    const unsigned long long* eb = (const unsigned long long*)out;  // entries in-place
    uint32_t bucket0 = (uint32_t)blk * P2B;
#pragma unroll
    for (int j = 0; j < P2B; ++j) {
        uint32_t ccount = cnt[bucket0 + j];
        if (ccount > EPB) ccount = EPB;
        const unsigned long long* ep = eb + (size_t)(bucket0 + j) * EPB;
        for (uint32_t k = threadIdx.x; k < ccount; k += 256) {
            unsigned long long e = ep[k];
            uint32_t off = (uint32_t)(e & 1023u);
            atomicMax(&lds[j * BUCKET_CELLS + off], e);
        }
    }
    __syncthreads();

    // Each thread produces one bitfield byte (8 consecutive cells) per iter.
#pragma unroll
    for (int it = 0; it < P2_CELLS / 8 / 256; ++it) {               // 4 iters
        int byteIdx = it * 256 + threadIdx.x;                       // [0, 1024)
        size_t cell = cellBase + (size_t)byteIdx * 8;
        float4 d0 = ((const float4*)density)[cell / 4];
        float4 d1 = ((const float4*)density)[cell / 4 + 1];
        float dd[8] = {d0.x, d0.y, d0.z, d0.w, d1.x, d1.y, d1.z, d1.w};
        float nv[8];
        uint32_t bf = 0u;
#pragma unroll
        for (int i = 0; i < 8; ++i) {
            unsigned long long e = lds[byteIdx * 8 + i];
            float d = dd[i];
            float v = d;
            if (e != 0ULL) {
                float s = __uint_as_float((uint32_t)(e >> 10));     // sigma bits
                if (d >= 0.0f && s >= 0.0f) v = fmaxf(d * 0.95f, s);
            }
            nv[i] = v;
            bf |= (v > 0.01f ? 1u : 0u) << i;
        }
        ((float4*)out)[cell / 4]     = make_float4(nv[0], nv[1], nv[2], nv[3]);
        ((float4*)out)[cell / 4 + 1] = make_float4(nv[4], nv[5], nv[6], nv[7]);
        out[GRID_ELEMS + cell / 8]   = (float)bf;
    }
}

// ---------------- fallback path (R1 pipeline, used only if ws too small) ----

__global__ void clear_tags(uint32_t* __restrict__ tags) {
    int t = blockIdx.x * blockDim.x + threadIdx.x;
    ((uint4*)tags)[t] = make_uint4(0u, 0u, 0u, 0u);
}

__global__ void scatter_tags(const int* __restrict__ coords,
                             uint32_t* __restrict__ tags) {
    int t = blockIdx.x * blockDim.x + threadIdx.x;
    const int4* c4 = (const int4*)coords;
    int4 a = c4[t * 3 + 0];
    int4 b = c4[t * 3 + 1];
    int4 c = c4[t * 3 + 2];
    int g    = t * 4;
    int casc = g >> 22;
    uint32_t n0 = (uint32_t)(g & (NUM_COORDS - 1));
    uint32_t* tg = tags + (size_t)casc * G3;
    uint32_t i0 = part1by2((uint32_t)a.x) | (part1by2((uint32_t)a.y) << 1) | (part1by2((uint32_t)a.z) << 2);
    uint32_t i1 = part1by2((uint32_t)a.w) | (part1by2((uint32_t)b.x) << 1) | (part1by2((uint32_t)b.y) << 2);
    uint32_t i2 = part1by2((uint32_t)b.z) | (part1by2((uint32_t)b.w) << 1) | (part1by2((uint32_t)c.x) << 2);
    uint32_t i3 = part1by2((uint32_t)c.y) | (part1by2((uint32_t)c.z) << 1) | (part1by2((uint32_t)c.w) << 2);
    atomicMax(&tg[i0], n0 + 1u);
    atomicMax(&tg[i1], n0 + 2u);
    atomicMax(&tg[i2], n0 + 3u);
    atomicMax(&tg[i3], n0 + 4u);
}

__global__ void finalize(float* __restrict__ out,
                         const float* __restrict__ density,
                         const float* __restrict__ sigmas) {
    int t = blockIdx.x * blockDim.x + threadIdx.x;
    uint4  tg0 = ((const uint4*)out)[t * 2 + 0];
    uint4  tg1 = ((const uint4*)out)[t * 2 + 1];
    float4 d0  = ((const float4*)density)[t * 2 + 0];
    float4 d1  = ((const float4*)density)[t * 2 + 1];
    int cell0 = t * 8;
    int casc  = cell0 >> 24;
    const float* sig = sigmas + (size_t)casc * NUM_COORDS;
    uint32_t tg[8] = {tg0.x, tg0.y, tg0.z, tg0.w, tg1.x, tg1.y, tg1.z, tg1.w};
    float    dd[8] = {d0.x, d0.y, d0.z, d0.w, d1.x, d1.y, d1.z, d1.w};
    float    nv[8];
    uint32_t byte = 0u;
#pragma unroll
    for (int i = 0; i < 8; ++i) {
        float d = dd[i];
        float v = d;
        uint32_t tag = tg[i];
        if (tag != 0u) {
            float s = sig[tag - 1u];
            if (d >= 0.0f && s >= 0.0f) v = fmaxf(d * 0.95f, s);
        }
        nv[i] = v;
        byte |= (v > 0.01f ? 1u : 0u) << i;
    }
    ((float4*)out)[t * 2 + 0] = make_float4(nv[0], nv[1], nv[2], nv[3]);
    ((float4*)out)[t * 2 + 1] = make_float4(nv[4], nv[5], nv[6], nv[7]);
    out[GRID_ELEMS + t] = (float)byte;
}

// ---------------- launch ----------------

extern "C" void kernel_launch(void* const* d_in, const int* in_sizes, int n_in,
                              void* d_out, int out_size, void* d_ws, size_t ws_size,
                              hipStream_t stream) {
    const float* density = (const float*)d_in[0];   // [3, 256^3] f32
    const float* sigmas  = (const float*)d_in[1];   // [3, 2^22]  f32
    const int*   coords  = (const int*)d_in[2];     // [3, 2^22, 3] i32
    float* out = (float*)d_out;

    if (ws_size >= (size_t)NBUCKETS * sizeof(uint32_t)) {
        uint32_t* cnt = (uint32_t*)d_ws;
        unsigned long long* entries = (unsigned long long*)d_out;  // staged in-place
        zero_cnt <<<NBUCKETS / 4 / 256,                256, 0, stream>>>(cnt);
        bucketize<<<CASCADES * NUM_COORDS / 4 / 256,   256, 0, stream>>>(coords, sigmas, cnt, entries);
        combine  <<<NBUCKETS / P2B,                    256, 0, stream>>>(out, density, cnt);
    } else {
        uint32_t* tags = (uint32_t*)d_out;
        clear_tags  <<<GRID_ELEMS / 4 / 256,            256, 0, stream>>>(tags);
        scatter_tags<<<CASCADES * NUM_COORDS / 4 / 256, 256, 0, stream>>>(coords, tags);
        finalize    <<<BF_ELEMS / 256,                  256, 0, stream>>>(out, density, sigmas);
    }
}